// Round 8
// baseline (151.787 us; speedup 1.0000x reference)
//
#include <hip/hip_runtime.h>
#include <hip/hip_bf16.h>

#define O_DIM 4096
#define I_DIM 4096
#define B_DIM 512

typedef short bf16x8 __attribute__((ext_vector_type(8)));
typedef float f32x4 __attribute__((ext_vector_type(4)));

__device__ __forceinline__ unsigned short f2bf(float x) {
    return __builtin_bit_cast(unsigned short, __float2bfloat16(x));
}

// ---------------------------------------------------------------------------
// Mask kernel — R1-exact (timed ~103 us = 4.7 TB/s logical; near the
// 7-stream floor. rocprof rows for this kernel are cold-L3 replay
// artifacts — ignore them).
// ---------------------------------------------------------------------------
__global__ __launch_bounds__(256) void mask_kernel(
    const float* __restrict__ wts,
    const float* __restrict__ pb, const float* __restrict__ pf,
    const float* __restrict__ pp, const float* __restrict__ noise,
    unsigned short* __restrict__ wm)
{
    const int total4 = (O_DIM * I_DIM) / 4;
    int stride = gridDim.x * blockDim.x;
    for (int q = blockIdx.x * blockDim.x + threadIdx.x; q < total4; q += stride) {
        float4 b4 = ((const float4*)pb)[q];
        float4 f4 = ((const float4*)pf)[q];
        float4 p4 = ((const float4*)pp)[q];
        float4 w4 = ((const float4*)wts)[q];
        float4 n0 = ((const float4*)noise)[(long)q*3 + 0];
        float4 n1 = ((const float4*)noise)[(long)q*3 + 1];
        float4 n2 = ((const float4*)noise)[(long)q*3 + 2];
        float lb[4] = {b4.x, b4.y, b4.z, b4.w};
        float lf[4] = {f4.x, f4.y, f4.z, f4.w};
        float lp[4] = {p4.x, p4.y, p4.z, p4.w};
        float wv[4] = {w4.x, w4.y, w4.z, w4.w};
        float uu[12] = {n0.x,n0.y,n0.z,n0.w, n1.x,n1.y,n1.z,n1.w, n2.x,n2.y,n2.z,n2.w};
        unsigned short out[4];
        #pragma unroll
        for (int j = 0; j < 4; ++j) {
            float u0 = uu[3*j+0], u1 = uu[3*j+1], u2 = uu[3*j+2];
            float t0 = lb[j] - __logf(-__logf(u0 + 1e-20f) + 1e-20f);
            float t1 = lf[j] - __logf(-__logf(u1 + 1e-20f) + 1e-20f);
            float t2 = lp[j] - __logf(-__logf(u2 + 1e-20f) + 1e-20f);
            int k = 0; float best = t0;
            if (t1 > best) { best = t1; k = 1; }
            if (t2 > best) { best = t2; k = 2; }
            float sec = (k == 0) ? fmaxf(t1, t2)
                      : (k == 1) ? fmaxf(t0, t2) : fmaxf(t0, t1);
            if (best - sec < 1e-3f) {  // near-tie: resolve in f64 (rare)
                double d0 = (double)lb[j] - log(-log((double)u0 + 1e-20) + 1e-20);
                double d1 = (double)lf[j] - log(-log((double)u1 + 1e-20) + 1e-20);
                double d2 = (double)lp[j] - log(-log((double)u2 + 1e-20) + 1e-20);
                k = 0; double db = d0;
                if (d1 > db) { db = d1; k = 1; }
                if (d2 > db) { k = 2; }
            }
            float mw = (k == 0) ? wv[j] : (k == 1) ? -wv[j] : 0.0f;
            out[j] = f2bf(mw);
        }
        ushort4 o4 = {out[0], out[1], out[2], out[3]};
        ((ushort4*)wm)[q] = o4;
    }
}

// ---------------------------------------------------------------------------
// x (f32) -> bf16
// ---------------------------------------------------------------------------
__global__ __launch_bounds__(256) void cvt_kernel(
    const float* __restrict__ x, unsigned short* __restrict__ xb)
{
    const int total4 = (B_DIM * I_DIM) / 4;
    int stride = gridDim.x * blockDim.x;
    for (int q = blockIdx.x * blockDim.x + threadIdx.x; q < total4; q += stride) {
        float4 v = ((const float4*)x)[q];
        ushort4 o = {f2bf(v.x), f2bf(v.y), f2bf(v.z), f2bf(v.w)};
        ((ushort4*)xb)[q] = o;
    }
}

// ---------------------------------------------------------------------------
// GEMM, 128x128 tile, split-K in one dispatch.
// 256 thr = 4 waves (2x2), each wave owns a 64x64 sub-tile (4x4 frags of
// 16x16x32) -> MFMA:ds_read = 32:16 per K-step (2:1, vs 1:1 at 64^2).
// Double-buffered LDS (64 KB -> 2 blocks/CU) staged with global_load_lds
// width=16; XOR-swizzle chunk^=(row&7) on global source + ds_read.
// nphase=4: grid 512 = 128 tiles x 4 K-phases, ALL co-resident in one
// execution wave. Phase 0 -> C0 (d_out raw), phase p>0 -> P[(p-1)].
// ---------------------------------------------------------------------------
#define BM 128
#define BN 128
#define BK 64
#define NTILES ((B_DIM / BM) * (O_DIM / BN))   // 4 * 32 = 128

__global__ __launch_bounds__(256, 2) void gemm_kernel(
    const unsigned short* __restrict__ A,   // xb [512][4096] bf16
    const unsigned short* __restrict__ Bw,  // wm [4096][4096] bf16
    float* __restrict__ C0, float* __restrict__ P, int nphase)
{
    __shared__ unsigned short Asm[2][BM * BK];  // 2 x 16 KB
    __shared__ unsigned short Bsm[2][BN * BK];  // 2 x 16 KB
    const int K = I_DIM;

    int idx = blockIdx.x;
    int kphase = idx >> 7;                  // idx / NTILES
    int tb     = idx & (NTILES - 1);
    int klen   = K / nphase;
    int kbeg   = kphase * klen;
    int nt     = klen / BK;
    float* __restrict__ Ct = (kphase == 0) ? C0
                           : &P[(size_t)(kphase - 1) * B_DIM * O_DIM];

    int tid = threadIdx.x;
    int w = tid >> 6, l = tid & 63;
    int bm0 = (tb & 3) * BM;                // 4 consecutive tb share bn
    int bn0 = (tb >> 2) * BN;
    int wr = w >> 1, wc = w & 1;            // 2x2 wave grid, 64x64 each
    int lrow = l & 15, lhi = l >> 4, swz = l & 7;

    int srow = l >> 3;                      // 0..7 within wave's 8 rows
    int schunk = (l & 7) ^ srow;            // inverse-swizzled source chunk

    f32x4 acc[4][4] = {};

#define STAGE(buf, k0)                                                         \
    {                                                                          \
        _Pragma("unroll")                                                      \
        for (int j = 0; j < 4; ++j) {                                          \
            int rr = j * 32 + w * 8 + srow;                                    \
            const unsigned short* sa = &A[(size_t)(bm0 + rr) * K + (k0) + schunk * 8];  \
            const unsigned short* sb = &Bw[(size_t)(bn0 + rr) * K + (k0) + schunk * 8]; \
            __builtin_amdgcn_global_load_lds(                                  \
                (const __attribute__((address_space(1))) void*)sa,             \
                (__attribute__((address_space(3))) void*)&Asm[buf][(j * 32 + w * 8) * BK], \
                16, 0, 0);                                                     \
            __builtin_amdgcn_global_load_lds(                                  \
                (const __attribute__((address_space(1))) void*)sb,             \
                (__attribute__((address_space(3))) void*)&Bsm[buf][(j * 32 + w * 8) * BK], \
                16, 0, 0);                                                     \
        }                                                                      \
    }

    STAGE(0, kbeg);
    __syncthreads();

    for (int t = 0; t < nt; ++t) {
        int cur = t & 1;
        if (t + 1 < nt) STAGE(cur ^ 1, kbeg + (t + 1) * BK);

        #pragma unroll
        for (int kk = 0; kk < 2; ++kk) {
            bf16x8 a[4], b[4];
            #pragma unroll
            for (int m = 0; m < 4; ++m)
                a[m] = *(const bf16x8*)&Asm[cur][(wr * 64 + m * 16 + lrow) * BK +
                                                 (((kk * 4 + lhi) ^ swz) * 8)];
            #pragma unroll
            for (int n = 0; n < 4; ++n)
                b[n] = *(const bf16x8*)&Bsm[cur][(wc * 64 + n * 16 + lrow) * BK +
                                                 (((kk * 4 + lhi) ^ swz) * 8)];
            #pragma unroll
            for (int m = 0; m < 4; ++m)
                #pragma unroll
                for (int n = 0; n < 4; ++n)
                    acc[m][n] = __builtin_amdgcn_mfma_f32_16x16x32_bf16(
                        a[m], b[n], acc[m][n], 0, 0, 0);
        }

        __syncthreads();
    }
#undef STAGE

    // epilogue: C frag row=(l>>4)*4+r, col=l&15 (m89-verified)
    int crow0 = bm0 + wr * 64 + lhi * 4;
    #pragma unroll
    for (int n = 0; n < 4; ++n) {
        int col = bn0 + wc * 64 + n * 16 + lrow;
        #pragma unroll
        for (int m = 0; m < 4; ++m)
            #pragma unroll
            for (int r = 0; r < 4; ++r)
                Ct[(size_t)(crow0 + m * 16 + r) * O_DIM + col] = acc[m][n][r];
    }
}

// ---------------------------------------------------------------------------
// Reduce: out = out(phase0) + sum_{p<nphase-1} P[p] + bias.
// ---------------------------------------------------------------------------
__global__ __launch_bounds__(256) void reduce_kernel(
    float* __restrict__ out, const float* __restrict__ P,
    const float* __restrict__ bias, int nphase)
{
    const int total4 = (B_DIM * O_DIM) / 4;
    const int BO4 = B_DIM * O_DIM / 4;
    int stride = gridDim.x * blockDim.x;
    for (int q = blockIdx.x * blockDim.x + threadIdx.x; q < total4; q += stride) {
        float4 v = ((const float4*)out)[q];
        float4 b = ((const float4*)bias)[q & (O_DIM / 4 - 1)];
        for (int p = 0; p + 1 < nphase; ++p) {
            float4 w = ((const float4*)P)[(size_t)p * BO4 + q];
            v.x += w.x; v.y += w.y; v.z += w.z; v.w += w.w;
        }
        v.x += b.x; v.y += b.y; v.z += b.z; v.w += b.w;
        ((float4*)out)[q] = v;
    }
}

extern "C" void kernel_launch(void* const* d_in, const int* in_sizes, int n_in,
                              void* d_out, int out_size, void* d_ws, size_t ws_size,
                              hipStream_t stream) {
    const float* x    = (const float*)d_in[0];
    const float* wts  = (const float*)d_in[1];
    const float* bias = (const float*)d_in[2];
    const float* pb   = (const float*)d_in[3];
    const float* pf   = (const float*)d_in[4];
    const float* pp   = (const float*)d_in[5];
    const float* un   = (const float*)d_in[6];
    float* out = (float*)d_out;

    unsigned short* wm = (unsigned short*)d_ws;              // 32 MB bf16 masked W
    unsigned short* xb = wm + (size_t)O_DIM * I_DIM;         // 4 MB bf16 x
    size_t p_off = ((size_t)O_DIM * I_DIM + (size_t)B_DIM * I_DIM) * 2;
    float* P = (float*)((char*)d_ws + p_off);                // up to 3x 8MB partials

    const size_t BO = (size_t)B_DIM * O_DIM * 4;
    int nphase = (ws_size >= p_off + 3 * BO) ? 4
               : (ws_size >= p_off + 1 * BO) ? 2 : 1;

    mask_kernel<<<2048, 256, 0, stream>>>(wts, pb, pf, pp, un, wm);
    cvt_kernel<<<512, 256, 0, stream>>>(x, xb);
    gemm_kernel<<<dim3(NTILES * nphase), 256, 0, stream>>>(xb, wm, out, P, nphase);
    reduce_kernel<<<2048, 256, 0, stream>>>(out, P, bias, nphase);
}

// Round 9
// 151.123 us; speedup vs baseline: 1.0044x; 1.0044x over previous
//
#include <hip/hip_runtime.h>
#include <hip/hip_bf16.h>

#define O_DIM 4096
#define I_DIM 4096
#define B_DIM 512

typedef short bf16x8 __attribute__((ext_vector_type(8)));
typedef float f32x4 __attribute__((ext_vector_type(4)));

__device__ __forceinline__ unsigned short f2bf(float x) {
    return __builtin_bit_cast(unsigned short, __float2bfloat16(x));
}

// ---------------------------------------------------------------------------
// Mask kernel — R1-exact (timed ~103 us = 4.7 TB/s logical, ~75% of the
// 2-stream copy ceiling; three structural variants failed to beat it ->
// treated as plateau. rocprof rows for this kernel are cold-L3 replay
// artifacts — ignore them).
// ---------------------------------------------------------------------------
__global__ __launch_bounds__(256) void mask_kernel(
    const float* __restrict__ wts,
    const float* __restrict__ pb, const float* __restrict__ pf,
    const float* __restrict__ pp, const float* __restrict__ noise,
    unsigned short* __restrict__ wm)
{
    const int total4 = (O_DIM * I_DIM) / 4;
    int stride = gridDim.x * blockDim.x;
    for (int q = blockIdx.x * blockDim.x + threadIdx.x; q < total4; q += stride) {
        float4 b4 = ((const float4*)pb)[q];
        float4 f4 = ((const float4*)pf)[q];
        float4 p4 = ((const float4*)pp)[q];
        float4 w4 = ((const float4*)wts)[q];
        float4 n0 = ((const float4*)noise)[(long)q*3 + 0];
        float4 n1 = ((const float4*)noise)[(long)q*3 + 1];
        float4 n2 = ((const float4*)noise)[(long)q*3 + 2];
        float lb[4] = {b4.x, b4.y, b4.z, b4.w};
        float lf[4] = {f4.x, f4.y, f4.z, f4.w};
        float lp[4] = {p4.x, p4.y, p4.z, p4.w};
        float wv[4] = {w4.x, w4.y, w4.z, w4.w};
        float uu[12] = {n0.x,n0.y,n0.z,n0.w, n1.x,n1.y,n1.z,n1.w, n2.x,n2.y,n2.z,n2.w};
        unsigned short out[4];
        #pragma unroll
        for (int j = 0; j < 4; ++j) {
            float u0 = uu[3*j+0], u1 = uu[3*j+1], u2 = uu[3*j+2];
            float t0 = lb[j] - __logf(-__logf(u0 + 1e-20f) + 1e-20f);
            float t1 = lf[j] - __logf(-__logf(u1 + 1e-20f) + 1e-20f);
            float t2 = lp[j] - __logf(-__logf(u2 + 1e-20f) + 1e-20f);
            int k = 0; float best = t0;
            if (t1 > best) { best = t1; k = 1; }
            if (t2 > best) { best = t2; k = 2; }
            float sec = (k == 0) ? fmaxf(t1, t2)
                      : (k == 1) ? fmaxf(t0, t2) : fmaxf(t0, t1);
            if (best - sec < 1e-3f) {  // near-tie: resolve in f64 (rare)
                double d0 = (double)lb[j] - log(-log((double)u0 + 1e-20) + 1e-20);
                double d1 = (double)lf[j] - log(-log((double)u1 + 1e-20) + 1e-20);
                double d2 = (double)lp[j] - log(-log((double)u2 + 1e-20) + 1e-20);
                k = 0; double db = d0;
                if (d1 > db) { db = d1; k = 1; }
                if (d2 > db) { k = 2; }
            }
            float mw = (k == 0) ? wv[j] : (k == 1) ? -wv[j] : 0.0f;
            out[j] = f2bf(mw);
        }
        ushort4 o4 = {out[0], out[1], out[2], out[3]};
        ((ushort4*)wm)[q] = o4;
    }
}

// ---------------------------------------------------------------------------
// x (f32) -> bf16
// ---------------------------------------------------------------------------
__global__ __launch_bounds__(256) void cvt_kernel(
    const float* __restrict__ x, unsigned short* __restrict__ xb)
{
    const int total4 = (B_DIM * I_DIM) / 4;
    int stride = gridDim.x * blockDim.x;
    for (int q = blockIdx.x * blockDim.x + threadIdx.x; q < total4; q += stride) {
        float4 v = ((const float4*)x)[q];
        ushort4 o = {f2bf(v.x), f2bf(v.y), f2bf(v.z), f2bf(v.w)};
        ((ushort4*)xb)[q] = o;
    }
}

// ---------------------------------------------------------------------------
// GEMM, 128x128 tile, split-K in one dispatch — R8 body + XCD-aware decode.
// HW maps XCD = blockIdx % 8 (round-robin). Decode so the 4 bm-sharers of
// each (bn, kphase) group get bids {c, c+8, c+16, c+24} + 32*i -> all on
// XCD c, and each XCD's B-working-set = (16 groups x 256KB at nphase=4)
// = 4 MB = exactly its L2. B-panel staging then hits L2 (~200cyc) instead
// of L3 (~500-900cyc), shortening the 2-phase vmcnt drain.
//   c = bid&7; bm = (bid>>3)&3; i = bid>>5;
//   kphase = c & (nphase-1); bn = (c>>log2(nphase))*(4*nphase) + i.
// ---------------------------------------------------------------------------
#define BM 128
#define BN 128
#define BK 64
#define NTILES ((B_DIM / BM) * (O_DIM / BN))   // 4 * 32 = 128

__global__ __launch_bounds__(256, 2) void gemm_kernel(
    const unsigned short* __restrict__ A,   // xb [512][4096] bf16
    const unsigned short* __restrict__ Bw,  // wm [4096][4096] bf16
    float* __restrict__ C0, float* __restrict__ P, int nphase, int lsp)
{
    __shared__ unsigned short Asm[2][BM * BK];  // 2 x 16 KB
    __shared__ unsigned short Bsm[2][BN * BK];  // 2 x 16 KB
    const int K = I_DIM;

    int bid = blockIdx.x;
    int c   = bid & 7;                      // XCD slot
    int bm  = (bid >> 3) & 3;
    int i   = bid >> 5;
    int kphase = c & (nphase - 1);
    int bn  = ((c >> lsp) << (2 + lsp)) + i;   // (c>>lsp)*(4*nphase) + i

    int klen   = K / nphase;
    int kbeg   = kphase * klen;
    int nt     = klen / BK;
    float* __restrict__ Ct = (kphase == 0) ? C0
                           : &P[(size_t)(kphase - 1) * B_DIM * O_DIM];

    int tid = threadIdx.x;
    int w = tid >> 6, l = tid & 63;
    int bm0 = bm * BM;
    int bn0 = bn * BN;
    int wr = w >> 1, wc = w & 1;            // 2x2 wave grid, 64x64 each
    int lrow = l & 15, lhi = l >> 4, swz = l & 7;

    int srow = l >> 3;                      // 0..7 within wave's 8 rows
    int schunk = (l & 7) ^ srow;            // inverse-swizzled source chunk

    f32x4 acc[4][4] = {};

#define STAGE(buf, k0)                                                         \
    {                                                                          \
        _Pragma("unroll")                                                      \
        for (int j = 0; j < 4; ++j) {                                          \
            int rr = j * 32 + w * 8 + srow;                                    \
            const unsigned short* sa = &A[(size_t)(bm0 + rr) * K + (k0) + schunk * 8];  \
            const unsigned short* sb = &Bw[(size_t)(bn0 + rr) * K + (k0) + schunk * 8]; \
            __builtin_amdgcn_global_load_lds(                                  \
                (const __attribute__((address_space(1))) void*)sa,             \
                (__attribute__((address_space(3))) void*)&Asm[buf][(j * 32 + w * 8) * BK], \
                16, 0, 0);                                                     \
            __builtin_amdgcn_global_load_lds(                                  \
                (const __attribute__((address_space(1))) void*)sb,             \
                (__attribute__((address_space(3))) void*)&Bsm[buf][(j * 32 + w * 8) * BK], \
                16, 0, 0);                                                     \
        }                                                                      \
    }

    STAGE(0, kbeg);
    __syncthreads();

    for (int t = 0; t < nt; ++t) {
        int cur = t & 1;
        if (t + 1 < nt) STAGE(cur ^ 1, kbeg + (t + 1) * BK);

        #pragma unroll
        for (int kk = 0; kk < 2; ++kk) {
            bf16x8 a[4], b[4];
            #pragma unroll
            for (int m = 0; m < 4; ++m)
                a[m] = *(const bf16x8*)&Asm[cur][(wr * 64 + m * 16 + lrow) * BK +
                                                 (((kk * 4 + lhi) ^ swz) * 8)];
            #pragma unroll
            for (int n = 0; n < 4; ++n)
                b[n] = *(const bf16x8*)&Bsm[cur][(wc * 64 + n * 16 + lrow) * BK +
                                                 (((kk * 4 + lhi) ^ swz) * 8)];
            #pragma unroll
            for (int m = 0; m < 4; ++m)
                #pragma unroll
                for (int n = 0; n < 4; ++n)
                    acc[m][n] = __builtin_amdgcn_mfma_f32_16x16x32_bf16(
                        a[m], b[n], acc[m][n], 0, 0, 0);
        }

        __syncthreads();
    }
#undef STAGE

    // epilogue: C frag row=(l>>4)*4+r, col=l&15 (m89-verified)
    int crow0 = bm0 + wr * 64 + lhi * 4;
    #pragma unroll
    for (int n = 0; n < 4; ++n) {
        int col = bn0 + wc * 64 + n * 16 + lrow;
        #pragma unroll
        for (int m = 0; m < 4; ++m)
            #pragma unroll
            for (int r = 0; r < 4; ++r)
                Ct[(size_t)(crow0 + m * 16 + r) * O_DIM + col] = acc[m][n][r];
    }
}

// ---------------------------------------------------------------------------
// Reduce: out = out(phase0) + sum_{p<nphase-1} P[p] + bias.
// ---------------------------------------------------------------------------
__global__ __launch_bounds__(256) void reduce_kernel(
    float* __restrict__ out, const float* __restrict__ P,
    const float* __restrict__ bias, int nphase)
{
    const int total4 = (B_DIM * O_DIM) / 4;
    const int BO4 = B_DIM * O_DIM / 4;
    int stride = gridDim.x * blockDim.x;
    for (int q = blockIdx.x * blockDim.x + threadIdx.x; q < total4; q += stride) {
        float4 v = ((const float4*)out)[q];
        float4 b = ((const float4*)bias)[q & (O_DIM / 4 - 1)];
        for (int p = 0; p + 1 < nphase; ++p) {
            float4 w = ((const float4*)P)[(size_t)p * BO4 + q];
            v.x += w.x; v.y += w.y; v.z += w.z; v.w += w.w;
        }
        v.x += b.x; v.y += b.y; v.z += b.z; v.w += b.w;
        ((float4*)out)[q] = v;
    }
}

extern "C" void kernel_launch(void* const* d_in, const int* in_sizes, int n_in,
                              void* d_out, int out_size, void* d_ws, size_t ws_size,
                              hipStream_t stream) {
    const float* x    = (const float*)d_in[0];
    const float* wts  = (const float*)d_in[1];
    const float* bias = (const float*)d_in[2];
    const float* pb   = (const float*)d_in[3];
    const float* pf   = (const float*)d_in[4];
    const float* pp   = (const float*)d_in[5];
    const float* un   = (const float*)d_in[6];
    float* out = (float*)d_out;

    unsigned short* wm = (unsigned short*)d_ws;              // 32 MB bf16 masked W
    unsigned short* xb = wm + (size_t)O_DIM * I_DIM;         // 4 MB bf16 x
    size_t p_off = ((size_t)O_DIM * I_DIM + (size_t)B_DIM * I_DIM) * 2;
    float* P = (float*)((char*)d_ws + p_off);                // up to 3x 8MB partials

    const size_t BO = (size_t)B_DIM * O_DIM * 4;
    int nphase = (ws_size >= p_off + 3 * BO) ? 4
               : (ws_size >= p_off + 1 * BO) ? 2 : 1;
    int lsp = (nphase == 4) ? 2 : (nphase == 2) ? 1 : 0;

    mask_kernel<<<2048, 256, 0, stream>>>(wts, pb, pf, pp, un, wm);
    cvt_kernel<<<512, 256, 0, stream>>>(x, xb);
    gemm_kernel<<<dim3(NTILES * nphase), 256, 0, stream>>>(xb, wm, out, P, nphase, lsp);
    reduce_kernel<<<2048, 256, 0, stream>>>(out, P, bias, nphase);
}

// Round 10
// 151.050 us; speedup vs baseline: 1.0049x; 1.0005x over previous
//
#include <hip/hip_runtime.h>
#include <hip/hip_bf16.h>

#define O_DIM 4096
#define I_DIM 4096
#define B_DIM 512
#define NQ ((O_DIM * I_DIM) / 4)
#define QPT 8   // quads per thread; 2048 blocks x 256 thr x 8 = NQ

typedef short bf16x8 __attribute__((ext_vector_type(8)));
typedef float f32x4 __attribute__((ext_vector_type(4)));

__device__ __forceinline__ unsigned short f2bf(float x) {
    return __builtin_bit_cast(unsigned short, __float2bfloat16(x));
}

// ---------------------------------------------------------------------------
// Mask kernel — R1 body, CONTIGUOUS-BLOCK index mapping.
// All prior variants iterated with an 8 MB stride (wave reads 1 KB then
// jumps 8 MB) -> ~14K random-ish 1KB bursts in flight -> HBM row-activate
// per burst, controller efficiency pinned at 1.6-1.8 TB/s cold across five
// otherwise-different variants. Here block b owns a contiguous quad range;
// per stream it walks 32 KB (96 KB noise) sequentially in 4 KB steps, giving
// the memory controller row-buffer locality. Body/compute unchanged.
// ---------------------------------------------------------------------------
__global__ __launch_bounds__(256) void mask_kernel(
    const float* __restrict__ wts,
    const float* __restrict__ pb, const float* __restrict__ pf,
    const float* __restrict__ pp, const float* __restrict__ noise,
    unsigned short* __restrict__ wm)
{
    const int base = blockIdx.x * (256 * QPT);
    #pragma unroll 1
    for (int i = 0; i < QPT; ++i) {
        const int q = base + i * 256 + threadIdx.x;
        float4 b4 = ((const float4*)pb)[q];
        float4 f4 = ((const float4*)pf)[q];
        float4 p4 = ((const float4*)pp)[q];
        float4 w4 = ((const float4*)wts)[q];
        float4 n0 = ((const float4*)noise)[(long)q*3 + 0];
        float4 n1 = ((const float4*)noise)[(long)q*3 + 1];
        float4 n2 = ((const float4*)noise)[(long)q*3 + 2];
        float lb[4] = {b4.x, b4.y, b4.z, b4.w};
        float lf[4] = {f4.x, f4.y, f4.z, f4.w};
        float lp[4] = {p4.x, p4.y, p4.z, p4.w};
        float wv[4] = {w4.x, w4.y, w4.z, w4.w};
        float uu[12] = {n0.x,n0.y,n0.z,n0.w, n1.x,n1.y,n1.z,n1.w, n2.x,n2.y,n2.z,n2.w};
        unsigned short out[4];
        #pragma unroll
        for (int j = 0; j < 4; ++j) {
            float u0 = uu[3*j+0], u1 = uu[3*j+1], u2 = uu[3*j+2];
            float t0 = lb[j] - __logf(-__logf(u0 + 1e-20f) + 1e-20f);
            float t1 = lf[j] - __logf(-__logf(u1 + 1e-20f) + 1e-20f);
            float t2 = lp[j] - __logf(-__logf(u2 + 1e-20f) + 1e-20f);
            int k = 0; float best = t0;
            if (t1 > best) { best = t1; k = 1; }
            if (t2 > best) { best = t2; k = 2; }
            float sec = (k == 0) ? fmaxf(t1, t2)
                      : (k == 1) ? fmaxf(t0, t2) : fmaxf(t0, t1);
            if (best - sec < 1e-3f) {  // near-tie: resolve in f64 (rare)
                double d0 = (double)lb[j] - log(-log((double)u0 + 1e-20) + 1e-20);
                double d1 = (double)lf[j] - log(-log((double)u1 + 1e-20) + 1e-20);
                double d2 = (double)lp[j] - log(-log((double)u2 + 1e-20) + 1e-20);
                k = 0; double db = d0;
                if (d1 > db) { db = d1; k = 1; }
                if (d2 > db) { k = 2; }
            }
            float mw = (k == 0) ? wv[j] : (k == 1) ? -wv[j] : 0.0f;
            out[j] = f2bf(mw);
        }
        ushort4 o4 = {out[0], out[1], out[2], out[3]};
        ((ushort4*)wm)[q] = o4;
    }
}

// ---------------------------------------------------------------------------
// x (f32) -> bf16
// ---------------------------------------------------------------------------
__global__ __launch_bounds__(256) void cvt_kernel(
    const float* __restrict__ x, unsigned short* __restrict__ xb)
{
    const int total4 = (B_DIM * I_DIM) / 4;
    int stride = gridDim.x * blockDim.x;
    for (int q = blockIdx.x * blockDim.x + threadIdx.x; q < total4; q += stride) {
        float4 v = ((const float4*)x)[q];
        ushort4 o = {f2bf(v.x), f2bf(v.y), f2bf(v.z), f2bf(v.w)};
        ((ushort4*)xb)[q] = o;
    }
}

// ---------------------------------------------------------------------------
// GEMM, 128x128 tile, split-K, XCD-aware decode (R9, unchanged).
// ---------------------------------------------------------------------------
#define BM 128
#define BN 128
#define BK 64
#define NTILES ((B_DIM / BM) * (O_DIM / BN))   // 4 * 32 = 128

__global__ __launch_bounds__(256, 2) void gemm_kernel(
    const unsigned short* __restrict__ A,   // xb [512][4096] bf16
    const unsigned short* __restrict__ Bw,  // wm [4096][4096] bf16
    float* __restrict__ C0, float* __restrict__ P, int nphase, int lsp)
{
    __shared__ unsigned short Asm[2][BM * BK];  // 2 x 16 KB
    __shared__ unsigned short Bsm[2][BN * BK];  // 2 x 16 KB
    const int K = I_DIM;

    int bid = blockIdx.x;
    int c   = bid & 7;                      // XCD slot
    int bm  = (bid >> 3) & 3;
    int i   = bid >> 5;
    int kphase = c & (nphase - 1);
    int bn  = ((c >> lsp) << (2 + lsp)) + i;   // (c>>lsp)*(4*nphase) + i

    int klen   = K / nphase;
    int kbeg   = kphase * klen;
    int nt     = klen / BK;
    float* __restrict__ Ct = (kphase == 0) ? C0
                           : &P[(size_t)(kphase - 1) * B_DIM * O_DIM];

    int tid = threadIdx.x;
    int w = tid >> 6, l = tid & 63;
    int bm0 = bm * BM;
    int bn0 = bn * BN;
    int wr = w >> 1, wc = w & 1;            // 2x2 wave grid, 64x64 each
    int lrow = l & 15, lhi = l >> 4, swz = l & 7;

    int srow = l >> 3;                      // 0..7 within wave's 8 rows
    int schunk = (l & 7) ^ srow;            // inverse-swizzled source chunk

    f32x4 acc[4][4] = {};

#define STAGE(buf, k0)                                                         \
    {                                                                          \
        _Pragma("unroll")                                                      \
        for (int j = 0; j < 4; ++j) {                                          \
            int rr = j * 32 + w * 8 + srow;                                    \
            const unsigned short* sa = &A[(size_t)(bm0 + rr) * K + (k0) + schunk * 8];  \
            const unsigned short* sb = &Bw[(size_t)(bn0 + rr) * K + (k0) + schunk * 8]; \
            __builtin_amdgcn_global_load_lds(                                  \
                (const __attribute__((address_space(1))) void*)sa,             \
                (__attribute__((address_space(3))) void*)&Asm[buf][(j * 32 + w * 8) * BK], \
                16, 0, 0);                                                     \
            __builtin_amdgcn_global_load_lds(                                  \
                (const __attribute__((address_space(1))) void*)sb,             \
                (__attribute__((address_space(3))) void*)&Bsm[buf][(j * 32 + w * 8) * BK], \
                16, 0, 0);                                                     \
        }                                                                      \
    }

    STAGE(0, kbeg);
    __syncthreads();

    for (int t = 0; t < nt; ++t) {
        int cur = t & 1;
        if (t + 1 < nt) STAGE(cur ^ 1, kbeg + (t + 1) * BK);

        #pragma unroll
        for (int kk = 0; kk < 2; ++kk) {
            bf16x8 a[4], b[4];
            #pragma unroll
            for (int m = 0; m < 4; ++m)
                a[m] = *(const bf16x8*)&Asm[cur][(wr * 64 + m * 16 + lrow) * BK +
                                                 (((kk * 4 + lhi) ^ swz) * 8)];
            #pragma unroll
            for (int n = 0; n < 4; ++n)
                b[n] = *(const bf16x8*)&Bsm[cur][(wc * 64 + n * 16 + lrow) * BK +
                                                 (((kk * 4 + lhi) ^ swz) * 8)];
            #pragma unroll
            for (int m = 0; m < 4; ++m)
                #pragma unroll
                for (int n = 0; n < 4; ++n)
                    acc[m][n] = __builtin_amdgcn_mfma_f32_16x16x32_bf16(
                        a[m], b[n], acc[m][n], 0, 0, 0);
        }

        __syncthreads();
    }
#undef STAGE

    // epilogue: C frag row=(l>>4)*4+r, col=l&15 (m89-verified)
    int crow0 = bm0 + wr * 64 + lhi * 4;
    #pragma unroll
    for (int n = 0; n < 4; ++n) {
        int col = bn0 + wc * 64 + n * 16 + lrow;
        #pragma unroll
        for (int m = 0; m < 4; ++m)
            #pragma unroll
            for (int r = 0; r < 4; ++r)
                Ct[(size_t)(crow0 + m * 16 + r) * O_DIM + col] = acc[m][n][r];
    }
}

// ---------------------------------------------------------------------------
// Reduce: out = out(phase0) + sum_{p<nphase-1} P[p] + bias.
// ---------------------------------------------------------------------------
__global__ __launch_bounds__(256) void reduce_kernel(
    float* __restrict__ out, const float* __restrict__ P,
    const float* __restrict__ bias, int nphase)
{
    const int total4 = (B_DIM * O_DIM) / 4;
    const int BO4 = B_DIM * O_DIM / 4;
    int stride = gridDim.x * blockDim.x;
    for (int q = blockIdx.x * blockDim.x + threadIdx.x; q < total4; q += stride) {
        float4 v = ((const float4*)out)[q];
        float4 b = ((const float4*)bias)[q & (O_DIM / 4 - 1)];
        for (int p = 0; p + 1 < nphase; ++p) {
            float4 w = ((const float4*)P)[(size_t)p * BO4 + q];
            v.x += w.x; v.y += w.y; v.z += w.z; v.w += w.w;
        }
        v.x += b.x; v.y += b.y; v.z += b.z; v.w += b.w;
        ((float4*)out)[q] = v;
    }
}

extern "C" void kernel_launch(void* const* d_in, const int* in_sizes, int n_in,
                              void* d_out, int out_size, void* d_ws, size_t ws_size,
                              hipStream_t stream) {
    const float* x    = (const float*)d_in[0];
    const float* wts  = (const float*)d_in[1];
    const float* bias = (const float*)d_in[2];
    const float* pb   = (const float*)d_in[3];
    const float* pf   = (const float*)d_in[4];
    const float* pp   = (const float*)d_in[5];
    const float* un   = (const float*)d_in[6];
    float* out = (float*)d_out;

    unsigned short* wm = (unsigned short*)d_ws;              // 32 MB bf16 masked W
    unsigned short* xb = wm + (size_t)O_DIM * I_DIM;         // 4 MB bf16 x
    size_t p_off = ((size_t)O_DIM * I_DIM + (size_t)B_DIM * I_DIM) * 2;
    float* P = (float*)((char*)d_ws + p_off);                // up to 3x 8MB partials

    const size_t BO = (size_t)B_DIM * O_DIM * 4;
    int nphase = (ws_size >= p_off + 3 * BO) ? 4
               : (ws_size >= p_off + 1 * BO) ? 2 : 1;
    int lsp = (nphase == 4) ? 2 : (nphase == 2) ? 1 : 0;

    mask_kernel<<<2048, 256, 0, stream>>>(wts, pb, pf, pp, un, wm);
    cvt_kernel<<<512, 256, 0, stream>>>(x, xb);
    gemm_kernel<<<dim3(NTILES * nphase), 256, 0, stream>>>(xb, wm, out, P, nphase, lsp);
    reduce_kernel<<<2048, 256, 0, stream>>>(out, P, bias, nphase);
}